// Round 6
// baseline (258.332 us; speedup 1.0000x reference)
//
#include <hip/hip_runtime.h>

#define I_DIM 2304
#define J_DIM 32
#define D_IN  8
#define E_DIM 16
#define B_DIM 64
#define BJE   (B_DIM * J_DIM * E_DIM)  // 32768
#define NC6   128
#define CH6   (I_DIM / NC6)            // 18
#define TILEW 4096                     // floats per W tile (32 j * 8 d * 16 e)

typedef const __attribute__((address_space(1))) char* gcp_t;
typedef __attribute__((address_space(3)))       char* lcp_t;

// grid = 512 (4 blocks per i-chunk: qb = bx>>7 picks b-quarter; chunk = bx&127
// -> the 4 blocks of a chunk are 128 apart = SAME XCD, share the W tile in L2).
// block = 256 thr = 4 waves. Wave covers 16 b? no: wave wv handles b = qb*16+wv*4+bb.
// Lane: jj = lane&31 (the j), eh = lane>>5 (e-half). Per lane: 4 b x 8 e.
// W tile staged by global_load_lds (0 VGPR) into LINEAR LDS, with the bank-
// swizzle XOR (u ^= row&15) pre-applied on the per-lane GLOBAL source address
// and re-applied on the read address (involution, m173/T2 pattern).
__global__ __launch_bounds__(256, 4) void caps_pass_v6(
    const float* __restrict__ x,    // [B, I, 8]
    const float* __restrict__ W,    // [I, J, 8, 16]
    const float* __restrict__ b0,   // [I, J]
    const float* __restrict__ Vacc, // [B, J, 16]
    float* __restrict__ partial)    // [NC6, B, J, 16]
{
    const int tid   = threadIdx.x;
    const int wv    = __builtin_amdgcn_readfirstlane(tid >> 6);  // wave 0..3 (SGPR)
    const int lane  = tid & 63;
    const int jj    = lane & 31;
    const int eh    = lane >> 5;     // e-half: e = eh*8 .. +8
    const int km    = jj & 15;       // swizzle key
    const int chunk = blockIdx.x & (NC6 - 1);
    const int qb    = blockIdx.x >> 7;       // b-quarter 0..3
    const int i0    = chunk * CH6;
    const int bbase = qb * 16 + wv * 4;

    __shared__ float Ws[2][TILEW];   // 32 KB, linear (no pad — swizzle instead)

    // ---- staging: 16 KB tile = 1024 16B-units; wave wv does units [(wv*4+r)*64 + lane]
    auto stage = [&](int buf, int itile) {
        const char* wt = (const char*)(W + (size_t)itile * TILEW);
#pragma unroll
        for (int r = 0; r < 4; ++r) {
            const int g    = (wv * 4 + r) * 64 + lane;          // dest unit (linear)
            const int srcu = (g & ~31) | ((g & 31) ^ ((g >> 5) & 15));  // swizzled src
            __builtin_amdgcn_global_load_lds(
                (gcp_t)(wt + (size_t)srcu * 16),
                (lcp_t)((char*)&Ws[buf][(wv * 4 + r) * 256]),
                16, 0, 0);
        }
    };

    // vacc[bb][e-half] — loaded once, stays in regs (L1 can't serve the
    // jj-divergent pattern cheaply; registers can)
    float vacc[4][8];
#pragma unroll
    for (int bb = 0; bb < 4; ++bb) {
        const float* vp = Vacc + ((size_t)((bbase + bb) * J_DIM + jj)) * E_DIM + eh * 8;
        const float4 v0 = *(const float4*)vp;
        const float4 v1 = *(const float4*)(vp + 4);
        vacc[bb][0]=v0.x; vacc[bb][1]=v0.y; vacc[bb][2]=v0.z; vacc[bb][3]=v0.w;
        vacc[bb][4]=v1.x; vacc[bb][5]=v1.y; vacc[bb][6]=v1.z; vacc[bb][7]=v1.w;
    }

    float Sacc[4][8];
#pragma unroll
    for (int bb = 0; bb < 4; ++bb)
#pragma unroll
        for (int e = 0; e < 8; ++e) Sacc[bb][e] = 0.f;

    stage(0, i0);
    __syncthreads();   // implicit vmcnt(0) drain -> tile 0 ready

    int cur = 0;
    for (int ii = 0; ii < CH6; ++ii) {
        const int i = i0 + ii;
        if (ii + 1 < CH6) stage(cur ^ 1, i + 1);   // async, lands by next barrier

        const float* wb = &Ws[cur][0];
        float uh[4][8];
#pragma unroll
        for (int bb = 0; bb < 4; ++bb)
#pragma unroll
            for (int e = 0; e < 8; ++e) uh[bb][e] = 0.f;

        // x[b][i][d]: wave-uniform addresses (bbase,i SGPR) -> scalar loads.
        // Two 16-float halves to cap live range (<=128 VGPR even if vectorized).
        float xq[4][4];
#pragma unroll
        for (int bb = 0; bb < 4; ++bb) {
            const float4 xl = *(const float4*)(x + ((size_t)(bbase + bb) * I_DIM + i) * D_IN);
            xq[bb][0]=xl.x; xq[bb][1]=xl.y; xq[bb][2]=xl.z; xq[bb][3]=xl.w;
        }
#pragma unroll
        for (int d = 0; d < 4; ++d) {
            const int u0 = (d << 2) | (eh << 1);
            const float4 wlo = *(const float4*)&wb[jj * 128 + (((u0    ) ^ km) << 2)];
            const float4 whi = *(const float4*)&wb[jj * 128 + (((u0 | 1) ^ km) << 2)];
#pragma unroll
            for (int bb = 0; bb < 4; ++bb) {
                const float xv = xq[bb][d];
                uh[bb][0] = fmaf(xv, wlo.x, uh[bb][0]);
                uh[bb][1] = fmaf(xv, wlo.y, uh[bb][1]);
                uh[bb][2] = fmaf(xv, wlo.z, uh[bb][2]);
                uh[bb][3] = fmaf(xv, wlo.w, uh[bb][3]);
                uh[bb][4] = fmaf(xv, whi.x, uh[bb][4]);
                uh[bb][5] = fmaf(xv, whi.y, uh[bb][5]);
                uh[bb][6] = fmaf(xv, whi.z, uh[bb][6]);
                uh[bb][7] = fmaf(xv, whi.w, uh[bb][7]);
            }
        }
#pragma unroll
        for (int bb = 0; bb < 4; ++bb) {
            const float4 xh = *(const float4*)(x + ((size_t)(bbase + bb) * I_DIM + i) * D_IN + 4);
            xq[bb][0]=xh.x; xq[bb][1]=xh.y; xq[bb][2]=xh.z; xq[bb][3]=xh.w;
        }
#pragma unroll
        for (int d = 4; d < 8; ++d) {
            const int u0 = (d << 2) | (eh << 1);
            const float4 wlo = *(const float4*)&wb[jj * 128 + (((u0    ) ^ km) << 2)];
            const float4 whi = *(const float4*)&wb[jj * 128 + (((u0 | 1) ^ km) << 2)];
#pragma unroll
            for (int bb = 0; bb < 4; ++bb) {
                const float xv = xq[bb][d - 4];
                uh[bb][0] = fmaf(xv, wlo.x, uh[bb][0]);
                uh[bb][1] = fmaf(xv, wlo.y, uh[bb][1]);
                uh[bb][2] = fmaf(xv, wlo.z, uh[bb][2]);
                uh[bb][3] = fmaf(xv, wlo.w, uh[bb][3]);
                uh[bb][4] = fmaf(xv, whi.x, uh[bb][4]);
                uh[bb][5] = fmaf(xv, whi.y, uh[bb][5]);
                uh[bb][6] = fmaf(xv, whi.z, uh[bb][6]);
                uh[bb][7] = fmaf(xv, whi.w, uh[bb][7]);
            }
        }

        const float b0v = b0[i * J_DIM + jj];
#pragma unroll
        for (int bb = 0; bb < 4; ++bb) {
            // logit = b0 + vacc . uh  (8 local + cross-e-half combine)
            float l0 = 0.f, l1 = 0.f;
#pragma unroll
            for (int e = 0; e < 8; e += 2) {
                l0 = fmaf(vacc[bb][e],     uh[bb][e],     l0);
                l1 = fmaf(vacc[bb][e + 1], uh[bb][e + 1], l1);
            }
            float lg = l0 + l1;
            lg += __shfl_xor(lg, 32);          // add other e-half
            const float l = b0v + lg;

            // softmax over jj (32 lanes of this e-half; masks <=16 stay in-half)
            float m = l;
#pragma unroll
            for (int k = 16; k >= 1; k >>= 1) m = fmaxf(m, __shfl_xor(m, k));
            const float p = __expf(l - m);
            float s = p;
#pragma unroll
            for (int k = 16; k >= 1; k >>= 1) s += __shfl_xor(s, k);
            const float c = p * __builtin_amdgcn_rcpf(s);

#pragma unroll
            for (int e = 0; e < 8; ++e) Sacc[bb][e] = fmaf(c, uh[bb][e], Sacc[bb][e]);
        }

        __syncthreads();   // drains the async stage; next tile ready
        cur ^= 1;
    }

#pragma unroll
    for (int bb = 0; bb < 4; ++bb) {
        float* pp = partial + (size_t)chunk * BJE
                  + ((size_t)((bbase + bb) * J_DIM + jj)) * E_DIM + eh * 8;
        *(float4*)pp       = make_float4(Sacc[bb][0], Sacc[bb][1], Sacc[bb][2], Sacc[bb][3]);
        *(float4*)(pp + 4) = make_float4(Sacc[bb][4], Sacc[bb][5], Sacc[bb][6], Sacc[bb][7]);
    }
}

// Sum partials over chunks (8 independent accumulators), then squash.
__global__ __launch_bounds__(256) void reduce_squash(
    const float* __restrict__ partial, float* __restrict__ Vacc,
    float* __restrict__ out, const int nc, const int final_it)
{
    const int t = blockIdx.x * blockDim.x + threadIdx.x;  // 0..BJE-1
    float a0=0.f,a1=0.f,a2=0.f,a3=0.f,a4=0.f,a5=0.f,a6=0.f,a7=0.f;
    for (int c = 0; c < nc; c += 8) {
        a0 += partial[(size_t)(c+0) * BJE + t];
        a1 += partial[(size_t)(c+1) * BJE + t];
        a2 += partial[(size_t)(c+2) * BJE + t];
        a3 += partial[(size_t)(c+3) * BJE + t];
        a4 += partial[(size_t)(c+4) * BJE + t];
        a5 += partial[(size_t)(c+5) * BJE + t];
        a6 += partial[(size_t)(c+6) * BJE + t];
        a7 += partial[(size_t)(c+7) * BJE + t];
    }
    const float acc = ((a0+a1)+(a2+a3)) + ((a4+a5)+(a6+a7));

    float s2 = acc * acc;
#pragma unroll
    for (int k = 8; k >= 1; k >>= 1) s2 += __shfl_xor(s2, k);  // reduce over e
    const float scale = s2 / (1.f + s2) * rsqrtf(s2 + 1e-7f);
    const float v = scale * acc;
    if (final_it) out[t] = v;
    else Vacc[t] += v;
}

extern "C" void kernel_launch(void* const* d_in, const int* in_sizes, int n_in,
                              void* d_out, int out_size, void* d_ws, size_t ws_size,
                              hipStream_t stream) {
    const float* x  = (const float*)d_in[0];   // [64,2304,8]
    const float* W  = (const float*)d_in[1];   // [2304,32,8,16]
    const float* b0 = (const float*)d_in[2];   // [2304,32]
    float* out = (float*)d_out;                // [64,32,16]

    // ws layout: partial[128][BJE] (16.8 MB) + Vacc[BJE] (128 KB).
    // ws proven >= 33.7 MB in rounds 3-5 (need256 branch executed).
    float* partial = (float*)d_ws;
    float* Vacc    = partial + (size_t)NC6 * BJE;

    hipMemsetAsync(Vacc, 0, BJE * sizeof(float), stream);

    for (int it = 0; it < 3; ++it) {
        caps_pass_v6<<<NC6 * 4, 256, 0, stream>>>(x, W, b0, Vacc, partial);
        reduce_squash<<<BJE / 256, 256, 0, stream>>>(partial, Vacc, out, NC6, it == 2 ? 1 : 0);
    }
}

// Round 7
// 183.292 us; speedup vs baseline: 1.4094x; 1.4094x over previous
//
#include <hip/hip_runtime.h>

#define I_DIM 2304
#define J_DIM 32
#define D_IN  8
#define E_DIM 16
#define B_DIM 64
#define BJE   (B_DIM * J_DIM * E_DIM)  // 32768
#define NC7   256
#define CH7   (I_DIM / NC7)            // 9
#define TILEW 4096                     // floats per 16KB W tile
#define XROW  (CH7 * D_IN)             // 72 floats of x per local b

typedef const __attribute__((address_space(1))) char* gcp_t;
typedef __attribute__((address_space(3)))       char* lcp_t;

// grid = 1024: chunk = bx&255 (9 i's), qb = bx>>8 (16 b's). Same-chunk blocks
// are 256 apart -> same XCD -> share the W tile via L2. Block = 256 thr =
// 4 waves; wave wv handles b = qb*16 + wv*4 + bb (bb<4); lane jj = j,
// eh = e-half. Hot loop reads ONLY LDS (x, b0, W staged) + issues the next
// W-tile DMA (global_load_lds, source-XOR-swizzled, linear LDS dest).
__global__ __launch_bounds__(256, 3) void caps_pass_v7(
    const float* __restrict__ x,    // [B, I, 8]
    const float* __restrict__ W,    // [I, J, 8, 16]
    const float* __restrict__ b0,   // [I, J]
    const float* __restrict__ Vacc, // [B, J, 16]
    float* __restrict__ partial)    // [NC7, B, J, 16]
{
    const int tid   = threadIdx.x;
    const int wv    = __builtin_amdgcn_readfirstlane(tid >> 6);  // 0..3 (SGPR)
    const int lane  = tid & 63;
    const int jj    = lane & 31;
    const int eh    = lane >> 5;
    const int km    = jj & 15;
    const int chunk = blockIdx.x & (NC7 - 1);
    const int qb    = blockIdx.x >> 8;
    const int i0    = chunk * CH7;
    const int bloc0 = wv * 4;           // local b base (SGPR)
    const int bbase = qb * 16 + bloc0;

    __shared__ float Ws[2][TILEW];        // 32 KB, linear (swizzle, no pad)
    __shared__ float Xall[16 * XROW];     // 4.6 KB: [bl][ii][d]
    __shared__ float B0s[CH7 * J_DIM];    // 1.15 KB: [ii][j]

    auto stage = [&](int buf, int itile) {
        const char* wt = (const char*)(W + (size_t)itile * TILEW);
#pragma unroll
        for (int r = 0; r < 4; ++r) {
            const int g    = (wv * 4 + r) * 64 + lane;                  // linear dest unit
            const int srcu = (g & ~31) | ((g & 31) ^ ((g >> 5) & 15));  // swizzled src
            __builtin_amdgcn_global_load_lds(
                (gcp_t)(wt + (size_t)srcu * 16),
                (lcp_t)((char*)&Ws[buf][(wv * 4 + r) * 256]),
                16, 0, 0);
        }
    };

    // ---- prologue staging (drained by the first barrier) ----
    stage(0, i0);
    if (tid < 16 * CH7) {                       // x rows: bl = tid/9, ii = tid%9
        const int bl = tid / CH7, ii = tid - bl * CH7;
        const float* xp = x + ((size_t)(qb * 16 + bl) * I_DIM + i0 + ii) * D_IN;
        const float4 a  = *(const float4*)xp;
        const float4 b4 = *(const float4*)(xp + 4);
        float* dq = &Xall[bl * XROW + ii * 8];
        *(float4*)dq = a; *(float4*)(dq + 4) = b4;
    }
    {                                           // b0 rows (288 elems)
        B0s[tid] = b0[(i0 + (tid >> 5)) * J_DIM + (tid & 31)];
        if (tid < CH7 * J_DIM - 256)
            B0s[256 + tid] = b0[(i0 + 8) * J_DIM + tid];
    }

    float vacc[4][8];
#pragma unroll
    for (int bb = 0; bb < 4; ++bb) {
        const float* vp = Vacc + ((size_t)((bbase + bb) * J_DIM + jj)) * E_DIM + eh * 8;
        const float4 v0 = *(const float4*)vp;
        const float4 v1 = *(const float4*)(vp + 4);
        vacc[bb][0]=v0.x; vacc[bb][1]=v0.y; vacc[bb][2]=v0.z; vacc[bb][3]=v0.w;
        vacc[bb][4]=v1.x; vacc[bb][5]=v1.y; vacc[bb][6]=v1.z; vacc[bb][7]=v1.w;
    }

    float Sacc[4][8];
#pragma unroll
    for (int bb = 0; bb < 4; ++bb)
#pragma unroll
        for (int e = 0; e < 8; ++e) Sacc[bb][e] = 0.f;

    __syncthreads();   // tile 0 + x + b0 visible

    int cur = 0;
    for (int ii = 0; ii < CH7; ++ii) {
        if (ii + 1 < CH7) stage(cur ^ 1, i0 + ii + 1);   // DMA hides under compute

        const float* wb = &Ws[cur][0];
        const float* xr = &Xall[bloc0 * XROW + ii * 8];

        float uh[4][8];
#pragma unroll
        for (int bb = 0; bb < 4; ++bb)
#pragma unroll
            for (int e = 0; e < 8; ++e) uh[bb][e] = 0.f;

        float xq[4][4];
#pragma unroll
        for (int bb = 0; bb < 4; ++bb) {      // wave-uniform LDS broadcast reads
            const float4 t = *(const float4*)(xr + bb * XROW);
            xq[bb][0]=t.x; xq[bb][1]=t.y; xq[bb][2]=t.z; xq[bb][3]=t.w;
        }
#pragma unroll
        for (int d = 0; d < 4; ++d) {
            const int u0 = (d << 2) | (eh << 1);
            const float4 wlo = *(const float4*)&wb[jj * 128 + (((u0    ) ^ km) << 2)];
            const float4 whi = *(const float4*)&wb[jj * 128 + (((u0 | 1) ^ km) << 2)];
#pragma unroll
            for (int bb = 0; bb < 4; ++bb) {
                const float xv = xq[bb][d];
                uh[bb][0] = fmaf(xv, wlo.x, uh[bb][0]);
                uh[bb][1] = fmaf(xv, wlo.y, uh[bb][1]);
                uh[bb][2] = fmaf(xv, wlo.z, uh[bb][2]);
                uh[bb][3] = fmaf(xv, wlo.w, uh[bb][3]);
                uh[bb][4] = fmaf(xv, whi.x, uh[bb][4]);
                uh[bb][5] = fmaf(xv, whi.y, uh[bb][5]);
                uh[bb][6] = fmaf(xv, whi.z, uh[bb][6]);
                uh[bb][7] = fmaf(xv, whi.w, uh[bb][7]);
            }
        }
#pragma unroll
        for (int bb = 0; bb < 4; ++bb) {
            const float4 t = *(const float4*)(xr + bb * XROW + 4);
            xq[bb][0]=t.x; xq[bb][1]=t.y; xq[bb][2]=t.z; xq[bb][3]=t.w;
        }
#pragma unroll
        for (int d = 4; d < 8; ++d) {
            const int u0 = (d << 2) | (eh << 1);
            const float4 wlo = *(const float4*)&wb[jj * 128 + (((u0    ) ^ km) << 2)];
            const float4 whi = *(const float4*)&wb[jj * 128 + (((u0 | 1) ^ km) << 2)];
#pragma unroll
            for (int bb = 0; bb < 4; ++bb) {
                const float xv = xq[bb][d - 4];
                uh[bb][0] = fmaf(xv, wlo.x, uh[bb][0]);
                uh[bb][1] = fmaf(xv, wlo.y, uh[bb][1]);
                uh[bb][2] = fmaf(xv, wlo.z, uh[bb][2]);
                uh[bb][3] = fmaf(xv, wlo.w, uh[bb][3]);
                uh[bb][4] = fmaf(xv, whi.x, uh[bb][4]);
                uh[bb][5] = fmaf(xv, whi.y, uh[bb][5]);
                uh[bb][6] = fmaf(xv, whi.z, uh[bb][6]);
                uh[bb][7] = fmaf(xv, whi.w, uh[bb][7]);
            }
        }

        const float b0v = B0s[ii * J_DIM + jj];
#pragma unroll
        for (int bb = 0; bb < 4; ++bb) {
            float l0 = 0.f, l1 = 0.f;
#pragma unroll
            for (int e = 0; e < 8; e += 2) {
                l0 = fmaf(vacc[bb][e],     uh[bb][e],     l0);
                l1 = fmaf(vacc[bb][e + 1], uh[bb][e + 1], l1);
            }
            float lg = l0 + l1;
            lg += __shfl_xor(lg, 32);                 // other e-half
            const float l = b0v + lg;

            // softmax over jj, no max-sub (|l| <= ~40, fp32-safe; exact-math equal)
            const float p = __expf(l);
            float s = p;
#pragma unroll
            for (int k = 16; k >= 1; k >>= 1) s += __shfl_xor(s, k);
            const float c = p * __builtin_amdgcn_rcpf(s);

#pragma unroll
            for (int e = 0; e < 8; ++e) Sacc[bb][e] = fmaf(c, uh[bb][e], Sacc[bb][e]);
        }

        __syncthreads();   // drains DMA; next tile ready; readers done with cur
        cur ^= 1;
    }

#pragma unroll
    for (int bb = 0; bb < 4; ++bb) {
        float* pp = partial + (size_t)chunk * BJE
                  + ((size_t)((bbase + bb) * J_DIM + jj)) * E_DIM + eh * 8;
        *(float4*)pp       = make_float4(Sacc[bb][0], Sacc[bb][1], Sacc[bb][2], Sacc[bb][3]);
        *(float4*)(pp + 4) = make_float4(Sacc[bb][4], Sacc[bb][5], Sacc[bb][6], Sacc[bb][7]);
    }
}

// Sum partials over chunks (8 independent accumulators), then squash.
__global__ __launch_bounds__(256) void reduce_squash(
    const float* __restrict__ partial, float* __restrict__ Vacc,
    float* __restrict__ out, const int nc, const int final_it)
{
    const int t = blockIdx.x * blockDim.x + threadIdx.x;  // 0..BJE-1
    float a0=0.f,a1=0.f,a2=0.f,a3=0.f,a4=0.f,a5=0.f,a6=0.f,a7=0.f;
    for (int c = 0; c < nc; c += 8) {
        a0 += partial[(size_t)(c+0) * BJE + t];
        a1 += partial[(size_t)(c+1) * BJE + t];
        a2 += partial[(size_t)(c+2) * BJE + t];
        a3 += partial[(size_t)(c+3) * BJE + t];
        a4 += partial[(size_t)(c+4) * BJE + t];
        a5 += partial[(size_t)(c+5) * BJE + t];
        a6 += partial[(size_t)(c+6) * BJE + t];
        a7 += partial[(size_t)(c+7) * BJE + t];
    }
    const float acc = ((a0+a1)+(a2+a3)) + ((a4+a5)+(a6+a7));

    float s2 = acc * acc;
#pragma unroll
    for (int k = 8; k >= 1; k >>= 1) s2 += __shfl_xor(s2, k);  // reduce over e
    const float scale = s2 / (1.f + s2) * rsqrtf(s2 + 1e-7f);
    const float v = scale * acc;
    if (final_it) out[t] = v;
    else Vacc[t] += v;
}

extern "C" void kernel_launch(void* const* d_in, const int* in_sizes, int n_in,
                              void* d_out, int out_size, void* d_ws, size_t ws_size,
                              hipStream_t stream) {
    const float* x  = (const float*)d_in[0];   // [64,2304,8]
    const float* W  = (const float*)d_in[1];   // [2304,32,8,16]
    const float* b0 = (const float*)d_in[2];   // [2304,32]
    float* out = (float*)d_out;                // [64,32,16]

    // ws layout: partial[256][BJE] (33.5 MB) + Vacc[BJE] (128 KB); ws proven
    // >= 33.7 MB in rounds 3-6.
    float* partial = (float*)d_ws;
    float* Vacc    = partial + (size_t)NC7 * BJE;

    hipMemsetAsync(Vacc, 0, BJE * sizeof(float), stream);

    for (int it = 0; it < 3; ++it) {
        caps_pass_v7<<<NC7 * 4, 256, 0, stream>>>(x, W, b0, Vacc, partial);
        reduce_squash<<<BJE / 256, 256, 0, stream>>>(partial, Vacc, out, NC7, it == 2 ? 1 : 0);
    }
}